// Round 4
// baseline (1872.526 us; speedup 1.0000x reference)
//
#include <hip/hip_runtime.h>

// 3-layer LSTM encoder. B=512, T=512, F=8, HID=128, EMB=64.
// MFMA recurrence: 32 blocks x 512 thr; block owns 16 batch rows.
// Per step: gates[16][G] = x_t @ Wih^T + h_t @ Whh^T via mfma_f32_16x16x32_f16
// (weight B-frags VGPR-resident; x-frags prefetched from prev layer's O in global;
//  h-frags from LDS). Pointwise gate math per-thread, c in registers.
// No input-projection kernels, no xp buffer. ws: O f16 [512][512][128] = 67MB.

#define DEVI __device__ __forceinline__

typedef _Float16 h8 __attribute__((ext_vector_type(8)));
typedef float f4 __attribute__((ext_vector_type(4)));

DEVI float sigmoidf_(float x) {
    return __builtin_amdgcn_rcpf(1.f + __builtin_amdgcn_exp2f(x * -1.44269504f));
}
DEVI float tanhf_(float x) {
    return 2.f * __builtin_amdgcn_rcpf(1.f + __builtin_amdgcn_exp2f(x * -2.88539008f)) - 1.f;
}

DEVI h8 cvt8(const float* p) {
    const float4 a = *reinterpret_cast<const float4*>(p);
    const float4 b = *reinterpret_cast<const float4*>(p + 4);
    return h8{(_Float16)a.x, (_Float16)a.y, (_Float16)a.z, (_Float16)a.w,
              (_Float16)b.x, (_Float16)b.y, (_Float16)b.z, (_Float16)b.w};
}

// LAYER=1: H=128, x from f32 input (K=8, zero-padded to one K-tile)
// LAYER=2: H=128, x from O (K=128), writes O in place
// LAYER=3: H=64,  x from O (K=128), writes final h to out at t=511
template <int LAYER>
__launch_bounds__(512, 2)
__global__ void lstm_k(const float* __restrict__ x, const _Float16* __restrict__ Oin,
                       const float* __restrict__ Wih, const float* __restrict__ Whh,
                       const float* __restrict__ bih, const float* __restrict__ bhh,
                       _Float16* __restrict__ Oout, float* __restrict__ out) {
    constexpr int T = 512;
    constexpr int H = (LAYER == 3) ? 64 : 128;
    constexpr int G = 4 * H;
    constexpr int KT_H = H / 32;               // K-tiles for h@Whh
    constexpr int KT_X = (LAYER == 1) ? 1 : 4; // K-tiles for x@Wih
    constexpr int KIN  = (LAYER == 1) ? 8 : 128;
    constexpr int NT = G / 128;                // N-tiles per wave (8 waves): 4 or 2
    constexpr int HP = H + 8;                  // padded h_lds row (f16)
    constexpr int RP = 20;                     // padded g_lds row: 16 rows + 4 (f32)
    constexpr int RT = H / 32;                 // pointwise rows/thread: 4 or 2

    const int tid  = threadIdx.x;
    const int lane = tid & 63;
    const int wv   = tid >> 6;        // wave 0..7
    const int lr   = lane & 15;       // fragment row/col
    const int lk   = lane >> 4;       // k-group 0..3
    const int b0   = blockIdx.x * 16;
    const int gbase = wv * (16 * NT); // this wave's gate-column base

    __shared__ __align__(16) float g_lds[G * RP];
    __shared__ __align__(16) _Float16 h_lds[16 * HP];

    // ---- resident weight B-frags (f32 -> f16 once) ----
    h8 wb[NT][KT_H];
#pragma unroll
    for (int nt = 0; nt < NT; nt++)
#pragma unroll
        for (int kt = 0; kt < KT_H; kt++)
            wb[nt][kt] = cvt8(Whh + (size_t)(gbase + nt * 16 + lr) * H + kt * 32 + lk * 8);

    h8 xb[NT][KT_X];
#pragma unroll
    for (int nt = 0; nt < NT; nt++)
#pragma unroll
        for (int kt = 0; kt < KT_X; kt++) {
            if (LAYER == 1 && lk != 0) {
                xb[nt][kt] = h8{};   // K=8 zero-padded: lanes with k>=8 hold 0
            } else {
                xb[nt][kt] = cvt8(Wih + (size_t)(gbase + nt * 16 + lr) * KIN + kt * 32 + lk * 8);
            }
        }

    // ---- pointwise thread mapping ----
    const int j  = tid & (H - 1);     // hidden index
    const int rg = tid / H;           // row group
    float bias[4], c[RT];
#pragma unroll
    for (int q = 0; q < 4; q++) bias[q] = bih[j + q * H] + bhh[j + q * H];
#pragma unroll
    for (int i = 0; i < RT; i++) c[i] = 0.f;

    for (int i = tid; i < 16 * HP; i += 512) h_lds[i] = (_Float16)0;
    __syncthreads();

    // ---- x-fragment loader (A-frag for time t) ----
    auto load_x = [&](int t, h8* xa) {
        if constexpr (LAYER == 1) {
            if (lk == 0)
                xa[0] = cvt8(x + ((size_t)(b0 + lr) * T + t) * 8);
            else
                xa[0] = h8{};
        } else {
#pragma unroll
            for (int kt = 0; kt < KT_X; kt++)
                xa[kt] = *reinterpret_cast<const h8*>(
                    Oin + ((size_t)(b0 + lr) * T + t) * 128 + kt * 32 + lk * 8);
        }
    };

    h8 xa[KT_X], xn[KT_X];
    load_x(0, xa);

    for (int t = 0; t < T; t++) {
        // ---- phase A: MFMA gates = x@Wih^T + h@Whh^T ----
        f4 acc[NT];
#pragma unroll
        for (int nt = 0; nt < NT; nt++) acc[nt] = f4{0.f, 0.f, 0.f, 0.f};
#pragma unroll
        for (int kt = 0; kt < KT_X; kt++)
#pragma unroll
            for (int nt = 0; nt < NT; nt++)
                acc[nt] = __builtin_amdgcn_mfma_f32_16x16x32_f16(xa[kt], xb[nt][kt], acc[nt], 0, 0, 0);

        load_x(t + 1 < T ? t + 1 : T - 1, xn);  // prefetch next step's x-frags

        h8 ha[KT_H];
#pragma unroll
        for (int kt = 0; kt < KT_H; kt++)
            ha[kt] = *reinterpret_cast<const h8*>(&h_lds[lr * HP + kt * 32 + lk * 8]);
#pragma unroll
        for (int kt = 0; kt < KT_H; kt++)
#pragma unroll
            for (int nt = 0; nt < NT; nt++)
                acc[nt] = __builtin_amdgcn_mfma_f32_16x16x32_f16(ha[kt], wb[nt][kt], acc[nt], 0, 0, 0);

        // C layout: col = gbase+nt*16+lr, rows lk*4..lk*4+3 -> transposed g_lds [col][row]
#pragma unroll
        for (int nt = 0; nt < NT; nt++)
            *reinterpret_cast<f4*>(&g_lds[(gbase + nt * 16 + lr) * RP + lk * 4]) = acc[nt];
        __syncthreads();

        // ---- phase B: pointwise LSTM cell ----
        float gv[4][RT];
#pragma unroll
        for (int q = 0; q < 4; q++) {
            if constexpr (RT == 4) {
                const f4 v = *reinterpret_cast<const f4*>(&g_lds[(j + q * H) * RP + rg * 4]);
                gv[q][0] = v[0]; gv[q][1] = v[1]; gv[q][2] = v[2]; gv[q][3] = v[3];
            } else {
                const float2 v = *reinterpret_cast<const float2*>(&g_lds[(j + q * H) * RP + rg * 2]);
                gv[q][0] = v.x; gv[q][1] = v.y;
            }
        }
#pragma unroll
        for (int i = 0; i < RT; i++) {
            const float gi = sigmoidf_(gv[0][i] + bias[0]);
            const float gf = sigmoidf_(gv[1][i] + bias[1]);
            const float gg = tanhf_(gv[2][i] + bias[2]);
            const float go = sigmoidf_(gv[3][i] + bias[3]);
            c[i] = gf * c[i] + gi * gg;
            const float h = go * tanhf_(c[i]);
            const int row = rg * RT + i;
            h_lds[row * HP + j] = (_Float16)h;
            if constexpr (LAYER < 3) {
                Oout[((size_t)(b0 + row) * T + t) * H + j] = (_Float16)h;
            } else {
                if (t == T - 1) out[(size_t)(b0 + row) * 64 + j] = h;
            }
        }
        __syncthreads();

#pragma unroll
        for (int kt = 0; kt < KT_X; kt++) xa[kt] = xn[kt];
    }
}

extern "C" void kernel_launch(void* const* d_in, const int* in_sizes, int n_in,
                              void* d_out, int out_size, void* d_ws, size_t ws_size,
                              hipStream_t stream) {
    const float* x    = (const float*)d_in[0];
    const float* Wih1 = (const float*)d_in[1];
    const float* Whh1 = (const float*)d_in[2];
    const float* bih1 = (const float*)d_in[3];
    const float* bhh1 = (const float*)d_in[4];
    const float* Wih2 = (const float*)d_in[5];
    const float* Whh2 = (const float*)d_in[6];
    const float* bih2 = (const float*)d_in[7];
    const float* bhh2 = (const float*)d_in[8];
    const float* Wih3 = (const float*)d_in[9];
    const float* Whh3 = (const float*)d_in[10];
    const float* bih3 = (const float*)d_in[11];
    const float* bhh3 = (const float*)d_in[12];
    float* out = (float*)d_out;

    _Float16* O = (_Float16*)d_ws;   // [512][512][128] f16 = 67,108,864 B
    (void)ws_size; (void)in_sizes; (void)n_in; (void)out_size;

    lstm_k<1><<<32, 512, 0, stream>>>(x, nullptr, Wih1, Whh1, bih1, bhh1, O, nullptr);
    lstm_k<2><<<32, 512, 0, stream>>>(nullptr, O, Wih2, Whh2, bih2, bhh2, O, nullptr);
    lstm_k<3><<<32, 512, 0, stream>>>(nullptr, O, Wih3, Whh3, bih3, bhh3, nullptr, out);
}

// Round 5
// 1449.278 us; speedup vs baseline: 1.2920x; 1.2920x over previous
//
#include <hip/hip_runtime.h>

// 3-layer LSTM encoder. B=512, T=512, F=8, HID=128, EMB=64.
// MFMA recurrence, gate-interleaved wave ownership: wave w owns hidden cols
// j in [w*16,(w+1)*16) for ALL FOUR gates -> after mfma_f32_16x16x32_f16 the
// full (i,f,g,o) of each cell sits in one lane's registers; LSTM cell update
// is pure-register (c[4]/lane). Only h round-trips via double-buffered padded
// LDS; ONE barrier per step. Per-layer kernels; O f16 [512][512][128] in ws.

#define DEVI __device__ __forceinline__

typedef _Float16 h8 __attribute__((ext_vector_type(8)));
typedef float f4 __attribute__((ext_vector_type(4)));

DEVI float sigmoidf_(float x) {
    return __builtin_amdgcn_rcpf(1.f + __builtin_amdgcn_exp2f(x * -1.44269504f));
}
DEVI float tanhf_(float x) {
    return 2.f * __builtin_amdgcn_rcpf(1.f + __builtin_amdgcn_exp2f(x * -2.88539008f)) - 1.f;
}

DEVI h8 cvt8(const float* p) {
    const float4 a = *reinterpret_cast<const float4*>(p);
    const float4 b = *reinterpret_cast<const float4*>(p + 4);
    return h8{(_Float16)a.x, (_Float16)a.y, (_Float16)a.z, (_Float16)a.w,
              (_Float16)b.x, (_Float16)b.y, (_Float16)b.z, (_Float16)b.w};
}

// LAYER=1: H=128, x from f32 input (K=8 zero-padded into one K-tile)
// LAYER=2: H=128, x from O (K=128), O updated in place (block-private rows)
// LAYER=3: H=64,  x from O (K=128), writes final h (t=511) to out f32
template <int LAYER>
__launch_bounds__(LAYER == 3 ? 256 : 512, 2)
__global__ void lstm_k(const float* __restrict__ x, const _Float16* __restrict__ Oin,
                       const float* __restrict__ Wih, const float* __restrict__ Whh,
                       const float* __restrict__ bih, const float* __restrict__ bhh,
                       _Float16* __restrict__ Oout, float* __restrict__ out) {
    constexpr int T = 512;
    constexpr int H = (LAYER == 3) ? 64 : 128;
    constexpr int KT_H = H / 32;               // K-tiles for h@Whh
    constexpr int KT_X = (LAYER == 1) ? 1 : 4; // K-tiles for x@Wih
    constexpr int HP = H + 8;                  // padded LDS row (f16): bank-balanced

    const int tid  = threadIdx.x;
    const int lane = tid & 63;
    const int wv   = tid >> 6;
    const int lr   = lane & 15;       // fragment row (batch) / col (j)
    const int lk   = lane >> 4;       // k-group 0..3
    const int b0   = blockIdx.x * 16;
    const int jcol = wv * 16 + lr;    // this lane's hidden column

    __shared__ __align__(16) _Float16 h_lds[2][16][HP];

    // ---- resident weight B-frags: gate q, K-tile kt ----
    h8 wbh[4][KT_H], wbx[4][KT_X];
#pragma unroll
    for (int q = 0; q < 4; q++) {
#pragma unroll
        for (int kt = 0; kt < KT_H; kt++)
            wbh[q][kt] = cvt8(Whh + (size_t)(q * H + jcol) * H + kt * 32 + lk * 8);
        if constexpr (LAYER == 1) {
            wbx[q][0] = (lk == 0) ? cvt8(Wih + (size_t)(q * H + jcol) * 8) : h8{};
        } else {
#pragma unroll
            for (int kt = 0; kt < KT_X; kt++)
                wbx[q][kt] = cvt8(Wih + (size_t)(q * H + jcol) * 128 + kt * 32 + lk * 8);
        }
    }

    float bias[4];
#pragma unroll
    for (int q = 0; q < 4; q++) bias[q] = bih[q * H + jcol] + bhh[q * H + jcol];

    float c[4] = {0.f, 0.f, 0.f, 0.f};

    for (int i = tid; i < 2 * 16 * HP; i += (LAYER == 3 ? 256 : 512))
        (&h_lds[0][0][0])[i] = (_Float16)0;
    __syncthreads();

    auto load_x = [&](int t, h8* xa) {
        if constexpr (LAYER == 1) {
            xa[0] = (lk == 0) ? cvt8(x + ((size_t)(b0 + lr) * T + t) * 8) : h8{};
        } else {
#pragma unroll
            for (int kt = 0; kt < KT_X; kt++)
                xa[kt] = *reinterpret_cast<const h8*>(
                    Oin + ((size_t)(b0 + lr) * T + t) * 128 + kt * 32 + lk * 8);
        }
    };

    h8 xa[KT_X], xn[KT_X];
    load_x(0, xa);

    for (int t = 0; t < T; t++) {
        const int cur = t & 1;
        f4 acc[4] = {f4{0.f, 0.f, 0.f, 0.f}, f4{0.f, 0.f, 0.f, 0.f},
                     f4{0.f, 0.f, 0.f, 0.f}, f4{0.f, 0.f, 0.f, 0.f}};

        // x @ Wih^T
#pragma unroll
        for (int kt = 0; kt < KT_X; kt++)
#pragma unroll
            for (int q = 0; q < 4; q++)
                acc[q] = __builtin_amdgcn_mfma_f32_16x16x32_f16(xa[kt], wbx[q][kt], acc[q], 0, 0, 0);

        if (t + 1 < T) load_x(t + 1, xn);   // prefetch next step's x

        // h @ Whh^T
        h8 ha[KT_H];
#pragma unroll
        for (int kt = 0; kt < KT_H; kt++)
            ha[kt] = *reinterpret_cast<const h8*>(&h_lds[cur][lr][kt * 32 + lk * 8]);
#pragma unroll
        for (int kt = 0; kt < KT_H; kt++)
#pragma unroll
            for (int q = 0; q < 4; q++)
                acc[q] = __builtin_amdgcn_mfma_f32_16x16x32_f16(ha[kt], wbh[q][kt], acc[q], 0, 0, 0);

        // ---- pure-register LSTM cell update: rows lk*4+i, col jcol ----
#pragma unroll
        for (int i = 0; i < 4; i++) {
            const float gi = sigmoidf_(acc[0][i] + bias[0]);
            const float gf = sigmoidf_(acc[1][i] + bias[1]);
            const float gg = tanhf_(acc[2][i] + bias[2]);
            const float go = sigmoidf_(acc[3][i] + bias[3]);
            c[i] = gf * c[i] + gi * gg;
            const float h = go * tanhf_(c[i]);
            const int row = lk * 4 + i;
            h_lds[cur ^ 1][row][jcol] = (_Float16)h;
            if constexpr (LAYER < 3) {
                Oout[((size_t)(b0 + row) * T + t) * 128 + jcol] = (_Float16)h;
            } else {
                if (t == T - 1) out[(size_t)(b0 + row) * 64 + jcol] = h;
            }
        }
        __syncthreads();

#pragma unroll
        for (int kt = 0; kt < KT_X; kt++) xa[kt] = xn[kt];
    }
}

extern "C" void kernel_launch(void* const* d_in, const int* in_sizes, int n_in,
                              void* d_out, int out_size, void* d_ws, size_t ws_size,
                              hipStream_t stream) {
    const float* x    = (const float*)d_in[0];
    const float* Wih1 = (const float*)d_in[1];
    const float* Whh1 = (const float*)d_in[2];
    const float* bih1 = (const float*)d_in[3];
    const float* bhh1 = (const float*)d_in[4];
    const float* Wih2 = (const float*)d_in[5];
    const float* Whh2 = (const float*)d_in[6];
    const float* bih2 = (const float*)d_in[7];
    const float* bhh2 = (const float*)d_in[8];
    const float* Wih3 = (const float*)d_in[9];
    const float* Whh3 = (const float*)d_in[10];
    const float* bih3 = (const float*)d_in[11];
    const float* bhh3 = (const float*)d_in[12];
    float* out = (float*)d_out;

    _Float16* O = (_Float16*)d_ws;   // [512][512][128] f16 = 67,108,864 B
    (void)ws_size; (void)in_sizes; (void)n_in; (void)out_size;

    lstm_k<1><<<32, 512, 0, stream>>>(x, nullptr, Wih1, Whh1, bih1, bhh1, O, nullptr);
    lstm_k<2><<<32, 512, 0, stream>>>(nullptr, O, Wih2, Whh2, bih2, bhh2, O, nullptr);
    lstm_k<3><<<32, 256, 0, stream>>>(nullptr, O, Wih3, Whh3, bih3, bhh3, nullptr, out);
}

// Round 6
// 847.315 us; speedup vs baseline: 2.2100x; 1.7104x over previous
//
#include <hip/hip_runtime.h>

// 3-layer LSTM encoder. B=512, T=512, F=8, HID=128, EMB=64.
// Single pipelined mega-kernel: 96 blocks = 3 stages x 32 batch-tiles.
// Stage structure = R5 (verified): gate-interleaved wave ownership, MFMA
// 16x16x32_f16, pure-register cell update, one barrier/step.
// Layers stream chunks (TC=32) to each other via O1/O2 f16 buffers with
// per-(layer,tile) progress flags (agent-scope atomics + threadfence).
// ws: [O1 67MB][O2 67MB][flags 64 ints]

#define DEVI __device__ __forceinline__

typedef _Float16 h8 __attribute__((ext_vector_type(8)));
typedef float f4 __attribute__((ext_vector_type(4)));

static constexpr int T_ = 512, TC_ = 32, NC_ = T_ / TC_;

DEVI float sigmoidf_(float x) {
    return __builtin_amdgcn_rcpf(1.f + __builtin_amdgcn_exp2f(x * -1.44269504f));
}
DEVI float tanhf_(float x) {
    return 2.f * __builtin_amdgcn_rcpf(1.f + __builtin_amdgcn_exp2f(x * -2.88539008f)) - 1.f;
}

DEVI h8 cvt8(const float* p) {
    const float4 a = *reinterpret_cast<const float4*>(p);
    const float4 b = *reinterpret_cast<const float4*>(p + 4);
    return h8{(_Float16)a.x, (_Float16)a.y, (_Float16)a.z, (_Float16)a.w,
              (_Float16)b.x, (_Float16)b.y, (_Float16)b.z, (_Float16)b.w};
}

// LAYER=1: H=128, x from f32 input (K=8 zero-padded), producer only
// LAYER=2: H=128, x from O1, writes O2, consumer+producer
// LAYER=3: H=64,  x from O2, writes out (t=511), consumer only; waves 4-7 idle
template <int LAYER>
DEVI void stage(int tile, char* smem, const float* x, const _Float16* Oin,
                const float* Wih, const float* Whh, const float* bih,
                const float* bhh, _Float16* Oout, float* out,
                int* flag_in, int* flag_out) {
    constexpr int H = (LAYER == 3) ? 64 : 128;
    constexpr int KT_H = H / 32;               // K-tiles for h@Whh
    constexpr int KT_X = (LAYER == 1) ? 1 : 4; // K-tiles for x@Wih
    constexpr int HP = H + 8;                  // padded LDS row (f16)
    constexpr int NWAVE = (LAYER == 3) ? 4 : 8;

    const int tid  = threadIdx.x;
    const int lane = tid & 63;
    const int wv   = tid >> 6;
    const int lr   = lane & 15;       // fragment row (batch) / col (j)
    const int lk   = lane >> 4;       // k-group 0..3
    const int b0   = tile * 16;
    const bool active = (wv < NWAVE);
    const int jcol = (wv & (NWAVE - 1)) * 16 + lr;

    _Float16 (*h_lds)[16][HP] = (_Float16 (*)[16][HP])smem;

    // ---- resident weight B-frags (f32 -> f16 once) ----
    h8 wbh[4][KT_H], wbx[4][KT_X];
    float bias[4];
    if (active) {
#pragma unroll
        for (int q = 0; q < 4; q++) {
#pragma unroll
            for (int kt = 0; kt < KT_H; kt++)
                wbh[q][kt] = cvt8(Whh + (size_t)(q * H + jcol) * H + kt * 32 + lk * 8);
            if constexpr (LAYER == 1) {
                wbx[q][0] = (lk == 0) ? cvt8(Wih + (size_t)(q * H + jcol) * 8) : h8{};
            } else {
#pragma unroll
                for (int kt = 0; kt < KT_X; kt++)
                    wbx[q][kt] = cvt8(Wih + (size_t)(q * H + jcol) * 128 + kt * 32 + lk * 8);
            }
            bias[q] = bih[q * H + jcol] + bhh[q * H + jcol];
        }
    }

    float c[4] = {0.f, 0.f, 0.f, 0.f};

    for (int i = tid; i < 2 * 16 * HP; i += 512) ((_Float16*)smem)[i] = (_Float16)0;
    __syncthreads();

    auto load_x = [&](int t, h8* xa) {
        if constexpr (LAYER == 1) {
            xa[0] = (lk == 0) ? cvt8(x + ((size_t)(b0 + lr) * T_ + t) * 8) : h8{};
        } else {
#pragma unroll
            for (int kt = 0; kt < KT_X; kt++)
                xa[kt] = *reinterpret_cast<const h8*>(
                    Oin + ((size_t)(b0 + lr) * T_ + t) * 128 + kt * 32 + lk * 8);
        }
    };

    h8 xa[KT_X], xn[KT_X];

    for (int ch = 0; ch < NC_; ch++) {
        // ---- consumer: wait for input chunk ch ----
        if constexpr (LAYER > 1) {
            if (tid == 0) {
                while (__hip_atomic_load(flag_in, __ATOMIC_RELAXED,
                                         __HIP_MEMORY_SCOPE_AGENT) < ch + 1)
                    __builtin_amdgcn_s_sleep(2);
                __threadfence();   // agent acquire: inv L1/L2 before data reads
            }
            __syncthreads();
        }
        if (active) load_x(ch * TC_, xa);

        for (int tt = 0; tt < TC_; tt++) {
            const int t = ch * TC_ + tt;
            const int cur = t & 1;
            if (active) {
                f4 acc[4] = {f4{0.f, 0.f, 0.f, 0.f}, f4{0.f, 0.f, 0.f, 0.f},
                             f4{0.f, 0.f, 0.f, 0.f}, f4{0.f, 0.f, 0.f, 0.f}};
                // x @ Wih^T
#pragma unroll
                for (int kt = 0; kt < KT_X; kt++)
#pragma unroll
                    for (int q = 0; q < 4; q++)
                        acc[q] = __builtin_amdgcn_mfma_f32_16x16x32_f16(xa[kt], wbx[q][kt], acc[q], 0, 0, 0);

                if (tt + 1 < TC_) load_x(t + 1, xn);   // prefetch within chunk

                // h @ Whh^T
                h8 ha[KT_H];
#pragma unroll
                for (int kt = 0; kt < KT_H; kt++)
                    ha[kt] = *reinterpret_cast<const h8*>(&h_lds[cur][lr][kt * 32 + lk * 8]);
#pragma unroll
                for (int kt = 0; kt < KT_H; kt++)
#pragma unroll
                    for (int q = 0; q < 4; q++)
                        acc[q] = __builtin_amdgcn_mfma_f32_16x16x32_f16(ha[kt], wbh[q][kt], acc[q], 0, 0, 0);

                // pure-register LSTM cell update: rows lk*4+i, col jcol
#pragma unroll
                for (int i = 0; i < 4; i++) {
                    const float gi = sigmoidf_(acc[0][i] + bias[0]);
                    const float gf = sigmoidf_(acc[1][i] + bias[1]);
                    const float gg = tanhf_(acc[2][i] + bias[2]);
                    const float go = sigmoidf_(acc[3][i] + bias[3]);
                    c[i] = gf * c[i] + gi * gg;
                    const float h = go * tanhf_(c[i]);
                    const int row = lk * 4 + i;
                    h_lds[cur ^ 1][row][jcol] = (_Float16)h;
                    if constexpr (LAYER < 3) {
                        Oout[((size_t)(b0 + row) * T_ + t) * 128 + jcol] = (_Float16)h;
                    } else {
                        if (t == T_ - 1) out[(size_t)(b0 + row) * 64 + jcol] = h;
                    }
                }
#pragma unroll
                for (int kt = 0; kt < KT_X; kt++) xa[kt] = xn[kt];
            }
            __syncthreads();   // also drains vmcnt: Oout stores complete at L2
        }

        // ---- producer: publish chunk ch ----
        if constexpr (LAYER < 3) {
            if (tid == 0) {
                __threadfence();   // agent release: wb L2 -> coherent point
                __hip_atomic_store(flag_out, ch + 1, __ATOMIC_RELAXED,
                                   __HIP_MEMORY_SCOPE_AGENT);
            }
        }
    }
}

__global__ __launch_bounds__(512, 1)
void mega_k(const float* __restrict__ x,
            const float* __restrict__ Wih1, const float* __restrict__ Whh1,
            const float* __restrict__ bih1, const float* __restrict__ bhh1,
            const float* __restrict__ Wih2, const float* __restrict__ Whh2,
            const float* __restrict__ bih2, const float* __restrict__ bhh2,
            const float* __restrict__ Wih3, const float* __restrict__ Whh3,
            const float* __restrict__ bih3, const float* __restrict__ bhh3,
            _Float16* __restrict__ O1, _Float16* __restrict__ O2,
            float* __restrict__ out, int* __restrict__ flags) {
    extern __shared__ char smem[];
    const int bid = blockIdx.x;
    if (bid < 32) {
        stage<1>(bid, smem, x, nullptr, Wih1, Whh1, bih1, bhh1, O1, nullptr,
                 nullptr, flags + bid);
    } else if (bid < 64) {
        stage<2>(bid - 32, smem, nullptr, O1, Wih2, Whh2, bih2, bhh2, O2, nullptr,
                 flags + (bid - 32), flags + 32 + (bid - 32));
    } else {
        stage<3>(bid - 64, smem, nullptr, O2, Wih3, Whh3, bih3, bhh3, nullptr, out,
                 flags + 32 + (bid - 64), nullptr);
    }
}

__global__ void zero_flags_k(int* flags) {
    if (threadIdx.x < 64)
        __hip_atomic_store(flags + threadIdx.x, 0, __ATOMIC_RELAXED,
                           __HIP_MEMORY_SCOPE_AGENT);
}

extern "C" void kernel_launch(void* const* d_in, const int* in_sizes, int n_in,
                              void* d_out, int out_size, void* d_ws, size_t ws_size,
                              hipStream_t stream) {
    const float* x    = (const float*)d_in[0];
    float* out = (float*)d_out;

    char* ws = (char*)d_ws;
    _Float16* O1 = (_Float16*)ws;                         // 67,108,864 B
    _Float16* O2 = (_Float16*)(ws + (size_t)67108864);    // 67,108,864 B
    int* flags   = (int*)(ws + (size_t)134217728);        // 256 B
    (void)ws_size; (void)in_sizes; (void)n_in; (void)out_size;

    zero_flags_k<<<1, 64, 0, stream>>>(flags);
    mega_k<<<96, 512, 8704, stream>>>(
        x,
        (const float*)d_in[1], (const float*)d_in[2], (const float*)d_in[3], (const float*)d_in[4],
        (const float*)d_in[5], (const float*)d_in[6], (const float*)d_in[7], (const float*)d_in[8],
        (const float*)d_in[9], (const float*)d_in[10], (const float*)d_in[11], (const float*)d_in[12],
        O1, O2, out, flags);
}

// Round 7
// 845.269 us; speedup vs baseline: 2.2153x; 1.0024x over previous
//
#include <hip/hip_runtime.h>

// 3-layer LSTM encoder. B=512, T=512, F=8, HID=128, EMB=64.
// Pipelined mega-kernel: 96 blocks = 3 stages x 32 batch-tiles (R6 structure).
// R7: in-loop barrier is lgkmcnt-only (s_waitcnt lgkmcnt(0); s_barrier) so the
// per-step global h-stores are NOT drained on the critical path; vmcnt is
// drained once per chunk before the release fence + flag. TC 32 -> 16.
// ws: [O1 67MB][O2 67MB][flags]

#define DEVI __device__ __forceinline__

typedef _Float16 h8 __attribute__((ext_vector_type(8)));
typedef float f4 __attribute__((ext_vector_type(4)));

static constexpr int T_ = 512, TC_ = 16, NC_ = T_ / TC_;

DEVI float sigmoidf_(float x) {
    return __builtin_amdgcn_rcpf(1.f + __builtin_amdgcn_exp2f(x * -1.44269504f));
}
DEVI float tanhf_(float x) {
    return 2.f * __builtin_amdgcn_rcpf(1.f + __builtin_amdgcn_exp2f(x * -2.88539008f)) - 1.f;
}

DEVI h8 cvt8(const float* p) {
    const float4 a = *reinterpret_cast<const float4*>(p);
    const float4 b = *reinterpret_cast<const float4*>(p + 4);
    return h8{(_Float16)a.x, (_Float16)a.y, (_Float16)a.z, (_Float16)a.w,
              (_Float16)b.x, (_Float16)b.y, (_Float16)b.z, (_Float16)b.w};
}

// LDS-only barrier: orders h_lds writes/reads without draining vmcnt
// (global stores stay in flight across steps).
DEVI void lds_barrier() {
    asm volatile("s_waitcnt lgkmcnt(0)\n\ts_barrier" ::: "memory");
}

// LAYER=1: H=128, x from f32 input (K=8 zero-padded), producer only
// LAYER=2: H=128, x from O1, writes O2, consumer+producer
// LAYER=3: H=64,  x from O2, writes out (t=511), consumer only; waves 4-7 idle
template <int LAYER>
DEVI void stage(int tile, char* smem, const float* x, const _Float16* Oin,
                const float* Wih, const float* Whh, const float* bih,
                const float* bhh, _Float16* Oout, float* out,
                int* flag_in, int* flag_out) {
    constexpr int H = (LAYER == 3) ? 64 : 128;
    constexpr int KT_H = H / 32;               // K-tiles for h@Whh
    constexpr int KT_X = (LAYER == 1) ? 1 : 4; // K-tiles for x@Wih
    constexpr int HP = H + 8;                  // padded LDS row (f16)
    constexpr int NWAVE = (LAYER == 3) ? 4 : 8;

    const int tid  = threadIdx.x;
    const int lane = tid & 63;
    const int wv   = tid >> 6;
    const int lr   = lane & 15;       // fragment row (batch) / col (j)
    const int lk   = lane >> 4;       // k-group 0..3
    const int b0   = tile * 16;
    const bool active = (wv < NWAVE);
    const int jcol = (wv & (NWAVE - 1)) * 16 + lr;

    _Float16 (*h_lds)[16][HP] = (_Float16 (*)[16][HP])smem;

    // ---- resident weight B-frags (f32 -> f16 once) ----
    h8 wbh[4][KT_H], wbx[4][KT_X];
    float bias[4];
    if (active) {
#pragma unroll
        for (int q = 0; q < 4; q++) {
#pragma unroll
            for (int kt = 0; kt < KT_H; kt++)
                wbh[q][kt] = cvt8(Whh + (size_t)(q * H + jcol) * H + kt * 32 + lk * 8);
            if constexpr (LAYER == 1) {
                wbx[q][0] = (lk == 0) ? cvt8(Wih + (size_t)(q * H + jcol) * 8) : h8{};
            } else {
#pragma unroll
                for (int kt = 0; kt < KT_X; kt++)
                    wbx[q][kt] = cvt8(Wih + (size_t)(q * H + jcol) * 128 + kt * 32 + lk * 8);
            }
            bias[q] = bih[q * H + jcol] + bhh[q * H + jcol];
        }
    }

    float c[4] = {0.f, 0.f, 0.f, 0.f};

    for (int i = tid; i < 2 * 16 * HP; i += 512) ((_Float16*)smem)[i] = (_Float16)0;
    __syncthreads();

    auto load_x = [&](int t, h8* xa) {
        if constexpr (LAYER == 1) {
            xa[0] = (lk == 0) ? cvt8(x + ((size_t)(b0 + lr) * T_ + t) * 8) : h8{};
        } else {
#pragma unroll
            for (int kt = 0; kt < KT_X; kt++)
                xa[kt] = *reinterpret_cast<const h8*>(
                    Oin + ((size_t)(b0 + lr) * T_ + t) * 128 + kt * 32 + lk * 8);
        }
    };

    h8 xa[KT_X], xn[KT_X];

    for (int ch = 0; ch < NC_; ch++) {
        // ---- consumer: wait for input chunk ch ----
        if constexpr (LAYER > 1) {
            if (tid == 0) {
                while (__hip_atomic_load(flag_in, __ATOMIC_RELAXED,
                                         __HIP_MEMORY_SCOPE_AGENT) < ch + 1)
                    __builtin_amdgcn_s_sleep(2);
                __threadfence();   // agent acquire: inv caches before data reads
            }
            __syncthreads();
        }
        if (active) load_x(ch * TC_, xa);

        for (int tt = 0; tt < TC_; tt++) {
            const int t = ch * TC_ + tt;
            const int cur = t & 1;
            if (active) {
                f4 acc[4] = {f4{0.f, 0.f, 0.f, 0.f}, f4{0.f, 0.f, 0.f, 0.f},
                             f4{0.f, 0.f, 0.f, 0.f}, f4{0.f, 0.f, 0.f, 0.f}};
                // x @ Wih^T
#pragma unroll
                for (int kt = 0; kt < KT_X; kt++)
#pragma unroll
                    for (int q = 0; q < 4; q++)
                        acc[q] = __builtin_amdgcn_mfma_f32_16x16x32_f16(xa[kt], wbx[q][kt], acc[q], 0, 0, 0);

                if (tt + 1 < TC_) load_x(t + 1, xn);   // prefetch within chunk

                // h @ Whh^T
                h8 ha[KT_H];
#pragma unroll
                for (int kt = 0; kt < KT_H; kt++)
                    ha[kt] = *reinterpret_cast<const h8*>(&h_lds[cur][lr][kt * 32 + lk * 8]);
#pragma unroll
                for (int kt = 0; kt < KT_H; kt++)
#pragma unroll
                    for (int q = 0; q < 4; q++)
                        acc[q] = __builtin_amdgcn_mfma_f32_16x16x32_f16(ha[kt], wbh[q][kt], acc[q], 0, 0, 0);

                // pure-register LSTM cell update: rows lk*4+i, col jcol
#pragma unroll
                for (int i = 0; i < 4; i++) {
                    const float gi = sigmoidf_(acc[0][i] + bias[0]);
                    const float gf = sigmoidf_(acc[1][i] + bias[1]);
                    const float gg = tanhf_(acc[2][i] + bias[2]);
                    const float go = sigmoidf_(acc[3][i] + bias[3]);
                    c[i] = gf * c[i] + gi * gg;
                    const float h = go * tanhf_(c[i]);
                    const int row = lk * 4 + i;
                    h_lds[cur ^ 1][row][jcol] = (_Float16)h;
                    if constexpr (LAYER < 3) {
                        Oout[((size_t)(b0 + row) * T_ + t) * 128 + jcol] = (_Float16)h;
                    } else {
                        if (t == T_ - 1) out[(size_t)(b0 + row) * 64 + jcol] = h;
                    }
                }
#pragma unroll
                for (int kt = 0; kt < KT_X; kt++) xa[kt] = xn[kt];
            }
            lds_barrier();   // LDS-only ordering: stores keep flying
        }

        // ---- producer: publish chunk ch (drain own stores first) ----
        if constexpr (LAYER < 3) {
            asm volatile("s_waitcnt vmcnt(0)" ::: "memory");
            __syncthreads();
            if (tid == 0) {
                __threadfence();   // agent release: visible at coherent point
                __hip_atomic_store(flag_out, ch + 1, __ATOMIC_RELAXED,
                                   __HIP_MEMORY_SCOPE_AGENT);
            }
        }
    }
}

__global__ __launch_bounds__(512, 1)
void mega_k(const float* __restrict__ x,
            const float* __restrict__ Wih1, const float* __restrict__ Whh1,
            const float* __restrict__ bih1, const float* __restrict__ bhh1,
            const float* __restrict__ Wih2, const float* __restrict__ Whh2,
            const float* __restrict__ bih2, const float* __restrict__ bhh2,
            const float* __restrict__ Wih3, const float* __restrict__ Whh3,
            const float* __restrict__ bih3, const float* __restrict__ bhh3,
            _Float16* __restrict__ O1, _Float16* __restrict__ O2,
            float* __restrict__ out, int* __restrict__ flags) {
    extern __shared__ char smem[];
    const int bid = blockIdx.x;
    if (bid < 32) {
        stage<1>(bid, smem, x, nullptr, Wih1, Whh1, bih1, bhh1, O1, nullptr,
                 nullptr, flags + bid);
    } else if (bid < 64) {
        stage<2>(bid - 32, smem, nullptr, O1, Wih2, Whh2, bih2, bhh2, O2, nullptr,
                 flags + (bid - 32), flags + 32 + (bid - 32));
    } else {
        stage<3>(bid - 64, smem, nullptr, O2, Wih3, Whh3, bih3, bhh3, nullptr, out,
                 flags + 32 + (bid - 64), nullptr);
    }
}

__global__ void zero_flags_k(int* flags) {
    if (threadIdx.x < 64)
        __hip_atomic_store(flags + threadIdx.x, 0, __ATOMIC_RELAXED,
                           __HIP_MEMORY_SCOPE_AGENT);
}

extern "C" void kernel_launch(void* const* d_in, const int* in_sizes, int n_in,
                              void* d_out, int out_size, void* d_ws, size_t ws_size,
                              hipStream_t stream) {
    const float* x    = (const float*)d_in[0];
    float* out = (float*)d_out;

    char* ws = (char*)d_ws;
    _Float16* O1 = (_Float16*)ws;                         // 67,108,864 B
    _Float16* O2 = (_Float16*)(ws + (size_t)67108864);    // 67,108,864 B
    int* flags   = (int*)(ws + (size_t)134217728);        // 256 B
    (void)ws_size; (void)in_sizes; (void)n_in; (void)out_size;

    zero_flags_k<<<1, 64, 0, stream>>>(flags);
    mega_k<<<96, 512, 8704, stream>>>(
        x,
        (const float*)d_in[1], (const float*)d_in[2], (const float*)d_in[3], (const float*)d_in[4],
        (const float*)d_in[5], (const float*)d_in[6], (const float*)d_in[7], (const float*)d_in[8],
        (const float*)d_in[9], (const float*)d_in[10], (const float*)d_in[11], (const float*)d_in[12],
        O1, O2, out, flags);
}

// Round 8
// 806.243 us; speedup vs baseline: 2.3225x; 1.0484x over previous
//
#include <hip/hip_runtime.h>

// 3-layer LSTM encoder. B=512, T=512, F=8, HID=128, EMB=64.
// Pipelined mega-kernel: 96 blocks = 3 stages x 32 batch-tiles.
// R8: x@Wih MFMA for step t+1 precomputed during step t's pointwise phase
// (x-path has no h dependence; MFMA pipe idle during trans) with bias folded
// into accumulator init; h ds_read issued first at barrier exit.
// In-loop barrier = lgkmcnt-only (global stores never drained per-step).
// ws: [O1 67MB][O2 67MB][flags]

#define DEVI __device__ __forceinline__

typedef _Float16 h8 __attribute__((ext_vector_type(8)));
typedef float f4 __attribute__((ext_vector_type(4)));

static constexpr int T_ = 512, TC_ = 16, NC_ = T_ / TC_;

DEVI float sigmoidf_(float x) {
    return __builtin_amdgcn_rcpf(1.f + __builtin_amdgcn_exp2f(x * -1.44269504f));
}
DEVI float tanhf_(float x) {
    return 2.f * __builtin_amdgcn_rcpf(1.f + __builtin_amdgcn_exp2f(x * -2.88539008f)) - 1.f;
}

DEVI h8 cvt8(const float* p) {
    const float4 a = *reinterpret_cast<const float4*>(p);
    const float4 b = *reinterpret_cast<const float4*>(p + 4);
    return h8{(_Float16)a.x, (_Float16)a.y, (_Float16)a.z, (_Float16)a.w,
              (_Float16)b.x, (_Float16)b.y, (_Float16)b.z, (_Float16)b.w};
}

// LDS-only barrier: orders h_lds writes/reads without draining vmcnt
// (global stores/loads stay in flight across steps).
DEVI void lds_barrier() {
    asm volatile("s_waitcnt lgkmcnt(0)\n\ts_barrier" ::: "memory");
}

// LAYER=1: H=128, x from f32 input (K=8 zero-padded), producer only
// LAYER=2: H=128, x from O1, writes O2, consumer+producer
// LAYER=3: H=64,  x from O2, writes out (t=511), consumer only; waves 4-7 idle
template <int LAYER>
DEVI void stage(int tile, char* smem, const float* x, const _Float16* Oin,
                const float* Wih, const float* Whh, const float* bih,
                const float* bhh, _Float16* Oout, float* out,
                int* flag_in, int* flag_out) {
    constexpr int H = (LAYER == 3) ? 64 : 128;
    constexpr int KT_H = H / 32;               // K-tiles for h@Whh
    constexpr int KT_X = (LAYER == 1) ? 1 : 4; // K-tiles for x@Wih
    constexpr int HP = H + 8;                  // padded LDS row (f16)
    constexpr int NWAVE = (LAYER == 3) ? 4 : 8;

    const int tid  = threadIdx.x;
    const int lane = tid & 63;
    const int wv   = tid >> 6;
    const int lr   = lane & 15;       // fragment row (batch) / col (j)
    const int lk   = lane >> 4;       // k-group 0..3
    const int b0   = tile * 16;
    const bool active = (wv < NWAVE);
    const int jcol = (wv & (NWAVE - 1)) * 16 + lr;

    _Float16 (*h_lds)[16][HP] = (_Float16 (*)[16][HP])smem;

    // ---- resident weight B-frags (f32 -> f16 once) ----
    h8 wbh[4][KT_H], wbx[4][KT_X];
    float bias[4];
    if (active) {
#pragma unroll
        for (int q = 0; q < 4; q++) {
#pragma unroll
            for (int kt = 0; kt < KT_H; kt++)
                wbh[q][kt] = cvt8(Whh + (size_t)(q * H + jcol) * H + kt * 32 + lk * 8);
            if constexpr (LAYER == 1) {
                wbx[q][0] = (lk == 0) ? cvt8(Wih + (size_t)(q * H + jcol) * 8) : h8{};
            } else {
#pragma unroll
                for (int kt = 0; kt < KT_X; kt++)
                    wbx[q][kt] = cvt8(Wih + (size_t)(q * H + jcol) * 128 + kt * 32 + lk * 8);
            }
            bias[q] = bih[q * H + jcol] + bhh[q * H + jcol];
        }
    }

    float c[4] = {0.f, 0.f, 0.f, 0.f};

    for (int i = tid; i < 2 * 16 * HP; i += 512) ((_Float16*)smem)[i] = (_Float16)0;
    __syncthreads();

    auto load_x = [&](int t, h8* xa) {
        if constexpr (LAYER == 1) {
            xa[0] = (lk == 0) ? cvt8(x + ((size_t)(b0 + lr) * T_ + t) * 8) : h8{};
        } else {
#pragma unroll
            for (int kt = 0; kt < KT_X; kt++)
                xa[kt] = *reinterpret_cast<const h8*>(
                    Oin + ((size_t)(b0 + lr) * T_ + t) * 128 + kt * 32 + lk * 8);
        }
    };

    // accx = bias + x_t @ Wih^T  (bias folded into accumulator init)
    auto xmfma = [&](const h8* xv, f4* ax) {
#pragma unroll
        for (int q = 0; q < 4; q++) ax[q] = f4{bias[q], bias[q], bias[q], bias[q]};
#pragma unroll
        for (int kt = 0; kt < KT_X; kt++)
#pragma unroll
            for (int q = 0; q < 4; q++)
                ax[q] = __builtin_amdgcn_mfma_f32_16x16x32_f16(xv[kt], wbx[q][kt], ax[q], 0, 0, 0);
    };

    h8 xa[KT_X], xn[KT_X];
    f4 accx[4];

    for (int ch = 0; ch < NC_; ch++) {
        // ---- consumer: wait for input chunk ch ----
        if constexpr (LAYER > 1) {
            if (tid == 0) {
                while (__hip_atomic_load(flag_in, __ATOMIC_RELAXED,
                                         __HIP_MEMORY_SCOPE_AGENT) < ch + 1)
                    __builtin_amdgcn_s_sleep(2);
                __threadfence();   // agent acquire: inv caches before data reads
            }
            __syncthreads();
        }
        if (active) {
            load_x(ch * TC_, xa);
            xmfma(xa, accx);       // chunk-head x-projection (unshadowed, 1/16 steps)
        }

        for (int tt = 0; tt < TC_; tt++) {
            const int t = ch * TC_ + tt;
            const int cur = t & 1;
            if (active) {
                // ---- issue h ds_read first: latency overlaps acc setup ----
                h8 ha[KT_H];
#pragma unroll
                for (int kt = 0; kt < KT_H; kt++)
                    ha[kt] = *reinterpret_cast<const h8*>(&h_lds[cur][lr][kt * 32 + lk * 8]);

                f4 acc[4];
#pragma unroll
                for (int q = 0; q < 4; q++) acc[q] = accx[q];

                // h @ Whh^T — the only matmul on the recurrent critical path
#pragma unroll
                for (int kt = 0; kt < KT_H; kt++)
#pragma unroll
                    for (int q = 0; q < 4; q++)
                        acc[q] = __builtin_amdgcn_mfma_f32_16x16x32_f16(ha[kt], wbh[q][kt], acc[q], 0, 0, 0);

                if (tt + 1 < TC_) load_x(t + 1, xn);   // prefetch next x

                // ---- pointwise LSTM cell update: rows lk*4+i, col jcol ----
#pragma unroll
                for (int i = 0; i < 4; i++) {
                    const float gi = sigmoidf_(acc[0][i]);
                    const float gf = sigmoidf_(acc[1][i]);
                    const float gg = tanhf_(acc[2][i]);
                    const float go = sigmoidf_(acc[3][i]);
                    c[i] = gf * c[i] + gi * gg;
                    const float h = go * tanhf_(c[i]);
                    const int row = lk * 4 + i;
                    h_lds[cur ^ 1][row][jcol] = (_Float16)h;
                    if constexpr (LAYER < 3) {
                        Oout[((size_t)(b0 + row) * T_ + t) * 128 + jcol] = (_Float16)h;
                    } else {
                        if (t == T_ - 1) out[(size_t)(b0 + row) * 64 + jcol] = h;
                    }
                }

                // ---- next step's x-projection in the trans-phase shadow ----
                if (tt + 1 < TC_) {
                    xmfma(xn, accx);
#pragma unroll
                    for (int kt = 0; kt < KT_X; kt++) xa[kt] = xn[kt];
                }
            }
            lds_barrier();   // LDS-only ordering: global ops keep flying
        }

        // ---- producer: publish chunk ch (drain own stores first) ----
        if constexpr (LAYER < 3) {
            asm volatile("s_waitcnt vmcnt(0)" ::: "memory");
            __syncthreads();
            if (tid == 0) {
                __threadfence();   // agent release: visible at coherent point
                __hip_atomic_store(flag_out, ch + 1, __ATOMIC_RELAXED,
                                   __HIP_MEMORY_SCOPE_AGENT);
            }
        }
    }
}

__global__ __launch_bounds__(512, 1)
void mega_k(const float* __restrict__ x,
            const float* __restrict__ Wih1, const float* __restrict__ Whh1,
            const float* __restrict__ bih1, const float* __restrict__ bhh1,
            const float* __restrict__ Wih2, const float* __restrict__ Whh2,
            const float* __restrict__ bih2, const float* __restrict__ bhh2,
            const float* __restrict__ Wih3, const float* __restrict__ Whh3,
            const float* __restrict__ bih3, const float* __restrict__ bhh3,
            _Float16* __restrict__ O1, _Float16* __restrict__ O2,
            float* __restrict__ out, int* __restrict__ flags) {
    extern __shared__ char smem[];
    const int bid = blockIdx.x;
    if (bid < 32) {
        stage<1>(bid, smem, x, nullptr, Wih1, Whh1, bih1, bhh1, O1, nullptr,
                 nullptr, flags + bid);
    } else if (bid < 64) {
        stage<2>(bid - 32, smem, nullptr, O1, Wih2, Whh2, bih2, bhh2, O2, nullptr,
                 flags + (bid - 32), flags + 32 + (bid - 32));
    } else {
        stage<3>(bid - 64, smem, nullptr, O2, Wih3, Whh3, bih3, bhh3, nullptr, out,
                 flags + 32 + (bid - 64), nullptr);
    }
}

__global__ void zero_flags_k(int* flags) {
    if (threadIdx.x < 64)
        __hip_atomic_store(flags + threadIdx.x, 0, __ATOMIC_RELAXED,
                           __HIP_MEMORY_SCOPE_AGENT);
}

extern "C" void kernel_launch(void* const* d_in, const int* in_sizes, int n_in,
                              void* d_out, int out_size, void* d_ws, size_t ws_size,
                              hipStream_t stream) {
    const float* x    = (const float*)d_in[0];
    float* out = (float*)d_out;

    char* ws = (char*)d_ws;
    _Float16* O1 = (_Float16*)ws;                         // 67,108,864 B
    _Float16* O2 = (_Float16*)(ws + (size_t)67108864);    // 67,108,864 B
    int* flags   = (int*)(ws + (size_t)134217728);        // 256 B
    (void)ws_size; (void)in_sizes; (void)n_in; (void)out_size;

    zero_flags_k<<<1, 64, 0, stream>>>(flags);
    mega_k<<<96, 512, 8704, stream>>>(
        x,
        (const float*)d_in[1], (const float*)d_in[2], (const float*)d_in[3], (const float*)d_in[4],
        (const float*)d_in[5], (const float*)d_in[6], (const float*)d_in[7], (const float*)d_in[8],
        (const float*)d_in[9], (const float*)d_in[10], (const float*)d_in[11], (const float*)d_in[12],
        O1, O2, out, flags);
}